// Round 4
// baseline (135.967 us; speedup 1.0000x reference)
//
#include <hip/hip_runtime.h>
#include <math.h>

// Problem constants
#define NB 4
#define HH 64
#define WW 64
#define CC 128
#define GG 4
#define GC 32
#define PP 9
#define MPIX (NB*HH*WW)          // 16384
#define PIXC ((size_t)MPIX*CC)   // 2097152 floats

typedef short  bf16x8 __attribute__((ext_vector_type(8)));
typedef ushort u16x8  __attribute__((ext_vector_type(8)));
typedef ushort u16x4  __attribute__((ext_vector_type(4)));
typedef float  f32x4  __attribute__((ext_vector_type(4)));

__device__ __forceinline__ ushort f2bf(float f) {
    uint u = __float_as_uint(f);
    u += 0x7FFFu + ((u >> 16) & 1u);     // round-to-nearest-even
    return (ushort)(u >> 16);
}
__device__ __forceinline__ float bf2f(ushort h) {
    return __uint_as_float(((uint)h) << 16);
}

// ---------------------------------------------------------------------------
// Prep: split each weight matrix into bf16 hi/lo, TRANSPOSED -> BT[mat][n][k].
// mat 0 = w_in, mat 1 = packed (w_off | w_mask | 0), mat 2 = w_out.
// ---------------------------------------------------------------------------
__global__ __launch_bounds__(256) void prep_weights(
    const float* __restrict__ w_in, const float* __restrict__ w_out,
    const float* __restrict__ w_off, const float* __restrict__ b_off,
    const float* __restrict__ w_mask, const float* __restrict__ b_mask,
    ushort* __restrict__ BT, float* __restrict__ bpack)
{
    int idx = blockIdx.x * 256 + threadIdx.x;
    if (idx < 3 * 128 * 32) {
        int m  = idx >> 12;
        int r  = idx & 4095;
        int n  = r >> 5;
        int k4 = (r & 31) << 2;
        ushort h[4], l[4];
#pragma unroll
        for (int j = 0; j < 4; j++) {
            int k = k4 + j;
            float a;
            if (m == 0)      a = w_in[k * 128 + n];
            else if (m == 2) a = w_out[k * 128 + n];
            else             a = (n < 72) ? w_off[k * 72 + n]
                               : (n < 108 ? w_mask[k * 36 + (n - 72)] : 0.f);
            ushort hh = f2bf(a);
            h[j] = hh;
            l[j] = f2bf(a - bf2f(hh));
        }
        ushort* dh = BT + m * 32768 + n * 128 + k4;   // hi plane
        ushort* dl = dh + 16384;                      // lo plane
        *(ushort4*)dh = make_ushort4(h[0], h[1], h[2], h[3]);
        *(ushort4*)dl = make_ushort4(l[0], l[1], l[2], l[3]);
    } else if (idx < 3 * 128 * 32 + 128) {
        int n = idx - 3 * 128 * 32;
        bpack[n] = (n < 72) ? b_off[n] : (n < 108 ? b_mask[n - 72] : 0.f);
    }
}

// ---------------------------------------------------------------------------
// Shared GEMM tail: C[rows x 128] += A(LDS, bf16 hi/lo swizzled) * B + bias.
// rows = MT*16. 4 waves, wave w owns cols [w*32, w*32+32). B frags in VGPRs,
// loaded straight from global BT planes (L1/L2-hot, reused by every block).
// LDS layout: plane p at p*MT*4096, row stride 256B, byte ^= (row&7)<<4.
// ---------------------------------------------------------------------------
template<int MT>
__device__ __forceinline__ void gemm_tail_lds(
    const ushort* __restrict__ BTh, const ushort* __restrict__ BTl,
    const float* __restrict__ bias, float* __restrict__ C,
    int row0, const char* sA)
{
    const int t  = threadIdx.x;
    const int wv = t >> 6;
    const int l  = t & 63;
    const int lr = l & 15;
    const int lk = l >> 4;
    const int planeBytes = MT * 16 * 256;

    bf16x8 bh[2][4], bl[2][4];
#pragma unroll
    for (int nt = 0; nt < 2; nt++) {
        const int n = wv * 32 + nt * 16 + lr;
#pragma unroll
        for (int ks = 0; ks < 4; ks++) {
            const int o = n * 128 + ks * 32 + lk * 8;
            bh[nt][ks] = *(const bf16x8*)(BTh + o);
            bl[nt][ks] = *(const bf16x8*)(BTl + o);
        }
    }

    f32x4 acc[MT][2];
#pragma unroll
    for (int m = 0; m < MT; m++) {
        acc[m][0] = (f32x4){0.f, 0.f, 0.f, 0.f};
        acc[m][1] = (f32x4){0.f, 0.f, 0.f, 0.f};
    }

#pragma unroll
    for (int ks = 0; ks < 4; ks++) {
        bf16x8 ah[MT], al[MT];
#pragma unroll
        for (int m = 0; m < MT; m++) {
            const int row = m * 16 + lr;
            const int off = row * 256 + ((((ks * 32 + lk * 8) * 2)) ^ ((row & 7) << 4));
            ah[m] = *(const bf16x8*)(sA + off);
            al[m] = *(const bf16x8*)(sA + planeBytes + off);
        }
#pragma unroll
        for (int m = 0; m < MT; m++) {
            acc[m][0] = __builtin_amdgcn_mfma_f32_16x16x32_bf16(ah[m], bh[0][ks], acc[m][0], 0, 0, 0);
            acc[m][1] = __builtin_amdgcn_mfma_f32_16x16x32_bf16(ah[m], bh[1][ks], acc[m][1], 0, 0, 0);
        }
#pragma unroll
        for (int m = 0; m < MT; m++) {
            acc[m][0] = __builtin_amdgcn_mfma_f32_16x16x32_bf16(al[m], bh[0][ks], acc[m][0], 0, 0, 0);
            acc[m][1] = __builtin_amdgcn_mfma_f32_16x16x32_bf16(al[m], bh[1][ks], acc[m][1], 0, 0, 0);
        }
#pragma unroll
        for (int m = 0; m < MT; m++) {
            acc[m][0] = __builtin_amdgcn_mfma_f32_16x16x32_bf16(ah[m], bl[0][ks], acc[m][0], 0, 0, 0);
            acc[m][1] = __builtin_amdgcn_mfma_f32_16x16x32_bf16(ah[m], bl[1][ks], acc[m][1], 0, 0, 0);
        }
    }

    // epilogue: C row = row0 + m*16 + lk*4 + i, col = wv*32 + nt*16 + lr
#pragma unroll
    for (int m = 0; m < MT; m++) {
#pragma unroll
        for (int nt = 0; nt < 2; nt++) {
            const int col = wv * 32 + nt * 16 + lr;
            const float bv = bias[col];
#pragma unroll
            for (int i = 0; i < 4; i++)
                C[(size_t)(row0 + m * 16 + lk * 4 + i) * 128 + col] = acc[m][nt][i] + bv;
        }
    }
}

// ---------------------------------------------------------------------------
// k1: input_proj. 32 rows/block, grid 512.
// Stage input rows as bf16 hi/lo into LDS, then GEMM tail -> x_proj (fp32).
// ---------------------------------------------------------------------------
__global__ __launch_bounds__(256) void k1_inproj(
    const float* __restrict__ A, const ushort* __restrict__ BTh,
    const ushort* __restrict__ BTl, const float* __restrict__ bias,
    float* __restrict__ C)
{
    __shared__ __align__(16) char sA[2 * 32 * 256];
    const int t = threadIdx.x;
    const int row0 = blockIdx.x * 32;

    const int row = t >> 3;              // 0..31
    const int ch0 = (t & 7) * 16;        // 0..112
    const float* src = A + (size_t)(row0 + row) * 128 + ch0;
    float f[16];
#pragma unroll
    for (int j = 0; j < 4; j++)
        *(float4*)(f + j * 4) = *(const float4*)(src + j * 4);
#pragma unroll
    for (int c = 0; c < 2; c++) {        // two 8-ch chunks
        u16x8 hv, lv;
#pragma unroll
        for (int j = 0; j < 8; j++) {
            const float v = f[c * 8 + j];
            const ushort hh = f2bf(v);
            hv[j] = hh;
            lv[j] = f2bf(v - bf2f(hh));
        }
        const int byte = row * 256 + (((ch0 + c * 8) * 2) ^ ((row & 7) << 4));
        *(u16x8*)(sA + byte) = hv;
        *(u16x8*)(sA + 32 * 256 + byte) = lv;
    }
    __syncthreads();
    gemm_tail_lds<2>(BTh, BTl, bias, C, row0, sA);
}

// ---------------------------------------------------------------------------
// k2: dwconv 3x3 + bias + LayerNorm + exact GELU, fused with offset/mask GEMM.
// 32 pixels/block (grid 512); 4 passes of 8 pixels x 32 lanes x 4 channels.
// ---------------------------------------------------------------------------
__global__ __launch_bounds__(256) void k2_dwln_off(
    const float* __restrict__ x, const float* __restrict__ kern,
    const float* __restrict__ kbias, const float* __restrict__ gamma,
    const float* __restrict__ beta, const ushort* __restrict__ BTh,
    const ushort* __restrict__ BTl, const float* __restrict__ bias,
    float* __restrict__ C)
{
    __shared__ __align__(16) char sA[2 * 32 * 256];
    const int t  = threadIdx.x;
    const int pl = t >> 5;               // 0..7
    const int cq = (t & 31) << 2;        // channel quad
    const int pix0 = blockIdx.x * 32;

#pragma unroll
    for (int pass = 0; pass < 4; pass++) {
        const int lpix = pass * 8 + pl;
        const int pix  = pix0 + lpix;
        const int w = pix & 63;
        const int h = (pix >> 6) & 63;
        const int b = pix >> 12;

        float4 acc = make_float4(0.f, 0.f, 0.f, 0.f);
#pragma unroll
        for (int kh = 0; kh < 3; kh++) {
            const int hy = h + kh - 1;
            if (hy < 0 || hy > 63) continue;
#pragma unroll
            for (int kw = 0; kw < 3; kw++) {
                const int wx = w + kw - 1;
                if (wx < 0 || wx > 63) continue;
                const float4 v  = *(const float4*)(x + (((size_t)((b * 64 + hy) * 64 + wx)) << 7) + cq);
                const float4 kv = *(const float4*)(kern + ((kh * 3 + kw) << 7) + cq);
                acc.x = fmaf(v.x, kv.x, acc.x);
                acc.y = fmaf(v.y, kv.y, acc.y);
                acc.z = fmaf(v.z, kv.z, acc.z);
                acc.w = fmaf(v.w, kv.w, acc.w);
            }
        }
        const float4 kb = *(const float4*)(kbias + cq);
        acc.x += kb.x; acc.y += kb.y; acc.z += kb.z; acc.w += kb.w;

        float s  = acc.x + acc.y + acc.z + acc.w;
        float s2 = acc.x * acc.x + acc.y * acc.y + acc.z * acc.z + acc.w * acc.w;
#pragma unroll
        for (int m = 16; m >= 1; m >>= 1) {
            s  += __shfl_xor(s, m);
            s2 += __shfl_xor(s2, m);
        }
        const float mu   = s * (1.f / 128.f);
        const float var  = s2 * (1.f / 128.f) - mu * mu;
        const float rstd = 1.f / sqrtf(var + 1e-6f);

        const float4 g  = *(const float4*)(gamma + cq);
        const float4 bb = *(const float4*)(beta + cq);
        const float vv[4] = {acc.x, acc.y, acc.z, acc.w};
        const float gg[4] = {g.x, g.y, g.z, g.w};
        const float be[4] = {bb.x, bb.y, bb.z, bb.w};
        u16x4 hv, lv;
#pragma unroll
        for (int i = 0; i < 4; i++) {
            const float xh = (vv[i] - mu) * rstd * gg[i] + be[i];
            const float gl = 0.5f * xh * (1.f + erff(xh * 0.70710678118654752f));
            const ushort hh = f2bf(gl);
            hv[i] = hh;
            lv[i] = f2bf(gl - bf2f(hh));
        }
        const int byte = lpix * 256 + ((cq * 2) ^ ((lpix & 7) << 4));
        *(u16x4*)(sA + byte) = hv;
        *(u16x4*)(sA + 32 * 256 + byte) = lv;
    }
    __syncthreads();
    gemm_tail_lds<2>(BTh, BTl, bias, C, pix0, sA);
}

// ---------------------------------------------------------------------------
// k3: DCNv3 sampling fused with output_proj GEMM.
// 16 pixels/block (grid 1024); thread = (pixel, group, 8-ch oct).
// ---------------------------------------------------------------------------
__global__ __launch_bounds__(256) void k3_sample_out(
    const float* __restrict__ xp, const float* __restrict__ om,
    const ushort* __restrict__ BTh, const ushort* __restrict__ BTl,
    const float* __restrict__ bias, float* __restrict__ out)
{
    __shared__ __align__(16) char sA[2 * 16 * 256];
    const int t = threadIdx.x;
    const int q = t & 3;
    const int g = (t >> 2) & 3;
    const int lpix = t >> 4;             // 0..15
    const int pix0 = blockIdx.x * 16;
    const int pix = pix0 + lpix;
    const int w = pix & 63;
    const int h = (pix >> 6) & 63;
    const int b = pix >> 12;

    const float* ompix = om + ((size_t)pix << 7);

    float lg[9];
    float mx = -1e30f;
#pragma unroll
    for (int p = 0; p < 9; p++) {
        lg[p] = ompix[72 + g * 9 + p];
        mx = fmaxf(mx, lg[p]);
    }
    float sum = 0.f;
#pragma unroll
    for (int p = 0; p < 9; p++) { lg[p] = expf(lg[p] - mx); sum += lg[p]; }
    const float inv = 1.f / sum;

    float4 acc0 = make_float4(0.f, 0.f, 0.f, 0.f);
    float4 acc1 = make_float4(0.f, 0.f, 0.f, 0.f);
    const int chbase = g * 32 + q * 8;

#pragma unroll
    for (int p = 0; p < 9; p++) {
        const float ox = ompix[g * 18 + 2 * p];
        const float oy = ompix[g * 18 + 2 * p + 1];
        const float px = (float)(w + p / 3 - 1) + ox;
        const float py = (float)(h + p % 3 - 1) + oy;
        const float fx0 = floorf(px), fy0 = floorf(py);
        const int x0 = (int)fx0, y0 = (int)fy0;
        const float wx1 = px - fx0, wy1 = py - fy0;
        const float wx0 = 1.f - wx1, wy0 = 1.f - wy1;
        const float m = lg[p] * inv;
        const float cw[4] = {wy0 * wx0 * m, wy0 * wx1 * m, wy1 * wx0 * m, wy1 * wx1 * m};
        const int cx[4] = {x0, x0 + 1, x0, x0 + 1};
        const int cy[4] = {y0, y0, y0 + 1, y0 + 1};
#pragma unroll
        for (int c = 0; c < 4; c++) {
            const int xx = cx[c], yy = cy[c];
            if (xx >= 0 && xx < 64 && yy >= 0 && yy < 64) {
                const float* src = xp + (((size_t)((b * 64 + yy) * 64 + xx)) << 7) + chbase;
                const float4 v0 = *(const float4*)(src);
                const float4 v1 = *(const float4*)(src + 4);
                const float wt = cw[c];
                acc0.x = fmaf(v0.x, wt, acc0.x); acc0.y = fmaf(v0.y, wt, acc0.y);
                acc0.z = fmaf(v0.z, wt, acc0.z); acc0.w = fmaf(v0.w, wt, acc0.w);
                acc1.x = fmaf(v1.x, wt, acc1.x); acc1.y = fmaf(v1.y, wt, acc1.y);
                acc1.z = fmaf(v1.z, wt, acc1.z); acc1.w = fmaf(v1.w, wt, acc1.w);
            }
        }
    }

    // write sampled 8ch as bf16 hi/lo into swizzled LDS
    const float sv[8] = {acc0.x, acc0.y, acc0.z, acc0.w, acc1.x, acc1.y, acc1.z, acc1.w};
    u16x8 hv, lv;
#pragma unroll
    for (int j = 0; j < 8; j++) {
        const ushort hh = f2bf(sv[j]);
        hv[j] = hh;
        lv[j] = f2bf(sv[j] - bf2f(hh));
    }
    const int byte = lpix * 256 + ((chbase * 2) ^ ((lpix & 7) << 4));
    *(u16x8*)(sA + byte) = hv;
    *(u16x8*)(sA + 16 * 256 + byte) = lv;
    __syncthreads();
    gemm_tail_lds<1>(BTh, BTl, bias, out, pix0, sA);
}

// ---------------------------------------------------------------------------
extern "C" void kernel_launch(void* const* d_in, const int* in_sizes, int n_in,
                              void* d_out, int out_size, void* d_ws, size_t ws_size,
                              hipStream_t stream)
{
    const float* input   = (const float*)d_in[0];
    const float* w_in    = (const float*)d_in[1];
    const float* b_in    = (const float*)d_in[2];
    const float* w_out   = (const float*)d_in[3];
    const float* b_out   = (const float*)d_in[4];
    const float* w_off   = (const float*)d_in[5];
    const float* b_off   = (const float*)d_in[6];
    const float* w_mask  = (const float*)d_in[7];
    const float* b_mask  = (const float*)d_in[8];
    const float* dw_kern = (const float*)d_in[9];
    const float* dw_bias = (const float*)d_in[10];
    const float* ln_g    = (const float*)d_in[11];
    const float* ln_b    = (const float*)d_in[12];
    float* out = (float*)d_out;

    float* ws      = (float*)d_ws;
    float* x_proj  = ws;                        // M*128
    float* offmask = ws + PIXC;                 // M*128 (72 off | 36 mask | 20 pad)
    ushort* BT     = (ushort*)(ws + 2 * PIXC);  // 3 mats x (hi|lo) x 128 x 128 bf16
    float* bpack   = (float*)(BT + 3 * 32768);  // 128

    prep_weights<<<49, 256, 0, stream>>>(w_in, w_out, w_off, b_off, w_mask, b_mask,
                                         BT, bpack);
    k1_inproj<<<MPIX / 32, 256, 0, stream>>>(input, BT, BT + 16384, b_in, x_proj);
    k2_dwln_off<<<MPIX / 32, 256, 0, stream>>>(input, dw_kern, dw_bias, ln_g, ln_b,
                                               BT + 32768, BT + 49152, bpack, offmask);
    k3_sample_out<<<MPIX / 16, 256, 0, stream>>>(x_proj, offmask,
                                                 BT + 65536, BT + 81920, b_out, out);
}

// Round 6
// 133.423 us; speedup vs baseline: 1.0191x; 1.0191x over previous
//
#include <hip/hip_runtime.h>
#include <math.h>

// Problem constants
#define NB 4
#define HH 64
#define WW 64
#define CC 128
#define GG 4
#define GC 32
#define PP 9
#define MPIX (NB*HH*WW)          // 16384
#define PIXC ((size_t)MPIX*CC)   // 2097152 floats

typedef short  bf16x8 __attribute__((ext_vector_type(8)));
typedef ushort u16x8  __attribute__((ext_vector_type(8)));
typedef ushort u16x4  __attribute__((ext_vector_type(4)));
typedef float  f32x4  __attribute__((ext_vector_type(4)));

__device__ __forceinline__ ushort f2bf(float f) {
    uint u = __float_as_uint(f);
    u += 0x7FFFu + ((u >> 16) & 1u);     // round-to-nearest-even
    return (ushort)(u >> 16);
}
__device__ __forceinline__ float bf2f(ushort h) {
    return __uint_as_float(((uint)h) << 16);
}

// ---------------------------------------------------------------------------
// Prep: split each weight matrix into bf16 hi/lo, TRANSPOSED -> BT[mat][n][k].
// mat 0 = w_in, mat 1 = packed (w_off | w_mask | 0), mat 2 = w_out.
// ---------------------------------------------------------------------------
__global__ __launch_bounds__(256) void prep_weights(
    const float* __restrict__ w_in, const float* __restrict__ w_out,
    const float* __restrict__ w_off, const float* __restrict__ b_off,
    const float* __restrict__ w_mask, const float* __restrict__ b_mask,
    ushort* __restrict__ BT, float* __restrict__ bpack)
{
    int idx = blockIdx.x * 256 + threadIdx.x;
    if (idx < 3 * 128 * 32) {
        int m  = idx >> 12;
        int r  = idx & 4095;
        int n  = r >> 5;
        int k4 = (r & 31) << 2;
        ushort h[4], l[4];
#pragma unroll
        for (int j = 0; j < 4; j++) {
            int k = k4 + j;
            float a;
            if (m == 0)      a = w_in[k * 128 + n];
            else if (m == 2) a = w_out[k * 128 + n];
            else             a = (n < 72) ? w_off[k * 72 + n]
                               : (n < 108 ? w_mask[k * 36 + (n - 72)] : 0.f);
            ushort hh = f2bf(a);
            h[j] = hh;
            l[j] = f2bf(a - bf2f(hh));
        }
        ushort* dh = BT + m * 32768 + n * 128 + k4;   // hi plane
        ushort* dl = dh + 16384;                      // lo plane
        *(ushort4*)dh = make_ushort4(h[0], h[1], h[2], h[3]);
        *(ushort4*)dl = make_ushort4(l[0], l[1], l[2], l[3]);
    } else if (idx < 3 * 128 * 32 + 128) {
        int n = idx - 3 * 128 * 32;
        bpack[n] = (n < 72) ? b_off[n] : (n < 108 ? b_mask[n - 72] : 0.f);
    }
}

// ---------------------------------------------------------------------------
// Shared GEMM tail: C[MT*16 x 128] = A(LDS bf16 hi/lo swizzled) * B + bias.
// NWAVES = 128/(NT*16). Wave wv owns cols [wv*NT*16, (wv+1)*NT*16).
// LDS: plane p at p*MT*4096, row stride 256B, byte ^= (row&7)<<4.
// ---------------------------------------------------------------------------
template<int MT, int NT>
__device__ __forceinline__ void gemm_tail_lds(
    const ushort* __restrict__ BTh, const ushort* __restrict__ BTl,
    const float* __restrict__ bias, float* __restrict__ C,
    int row0, const char* sA)
{
    const int t  = threadIdx.x;
    const int wv = t >> 6;
    const int l  = t & 63;
    const int lr = l & 15;
    const int lk = l >> 4;
    const int colbase = wv * (NT * 16);
    const int planeBytes = MT * 16 * 256;

    bf16x8 bh[NT][4], bl[NT][4];
#pragma unroll
    for (int nt = 0; nt < NT; nt++) {
        const int n = colbase + nt * 16 + lr;
#pragma unroll
        for (int ks = 0; ks < 4; ks++) {
            const int o = n * 128 + ks * 32 + lk * 8;
            bh[nt][ks] = *(const bf16x8*)(BTh + o);
            bl[nt][ks] = *(const bf16x8*)(BTl + o);
        }
    }

    f32x4 acc[MT][NT];
#pragma unroll
    for (int m = 0; m < MT; m++)
#pragma unroll
        for (int nt = 0; nt < NT; nt++) acc[m][nt] = (f32x4){0.f, 0.f, 0.f, 0.f};

#pragma unroll
    for (int ks = 0; ks < 4; ks++) {
        bf16x8 ah[MT], al[MT];
#pragma unroll
        for (int m = 0; m < MT; m++) {
            const int row = m * 16 + lr;
            const int off = row * 256 + (((ks * 64 + lk * 16)) ^ ((row & 7) << 4));
            ah[m] = *(const bf16x8*)(sA + off);
            al[m] = *(const bf16x8*)(sA + planeBytes + off);
        }
#pragma unroll
        for (int m = 0; m < MT; m++)
#pragma unroll
            for (int nt = 0; nt < NT; nt++)
                acc[m][nt] = __builtin_amdgcn_mfma_f32_16x16x32_bf16(ah[m], bh[nt][ks], acc[m][nt], 0, 0, 0);
#pragma unroll
        for (int m = 0; m < MT; m++)
#pragma unroll
            for (int nt = 0; nt < NT; nt++)
                acc[m][nt] = __builtin_amdgcn_mfma_f32_16x16x32_bf16(al[m], bh[nt][ks], acc[m][nt], 0, 0, 0);
#pragma unroll
        for (int m = 0; m < MT; m++)
#pragma unroll
            for (int nt = 0; nt < NT; nt++)
                acc[m][nt] = __builtin_amdgcn_mfma_f32_16x16x32_bf16(ah[m], bl[nt][ks], acc[m][nt], 0, 0, 0);
    }

    // epilogue: C row = row0 + m*16 + lk*4 + i, col = colbase + nt*16 + lr
#pragma unroll
    for (int m = 0; m < MT; m++) {
#pragma unroll
        for (int nt = 0; nt < NT; nt++) {
            const int col = colbase + nt * 16 + lr;
            const float bv = bias[col];
#pragma unroll
            for (int i = 0; i < 4; i++)
                C[(size_t)(row0 + m * 16 + lk * 4 + i) * 128 + col] = acc[m][nt][i] + bv;
        }
    }
}

// ---------------------------------------------------------------------------
// k12: input_proj GEMM  +  (dwconv 3x3 + LN + GELU -> offset/mask GEMM),
// fused: both phases share this block's 32 pixels. Grid 512, 256 threads.
// ---------------------------------------------------------------------------
__global__ __launch_bounds__(256) void k12_proj_dwln(
    const float* __restrict__ x, const ushort* __restrict__ BT0h,
    const ushort* __restrict__ BT0l, const float* __restrict__ b_in,
    float* __restrict__ x_proj,
    const float* __restrict__ kern, const float* __restrict__ kbias,
    const float* __restrict__ gamma, const float* __restrict__ beta,
    const ushort* __restrict__ BT1h, const ushort* __restrict__ BT1l,
    const float* __restrict__ bpack, float* __restrict__ offmask)
{
    __shared__ __align__(16) char sA[2 * 32 * 256];
    const int t = threadIdx.x;
    const int pix0 = blockIdx.x * 32;

    // ---- phase A: stage input rows as bf16 hi/lo, then input_proj GEMM ----
    {
        const int row = t >> 3;              // 0..31
        const int ch0 = (t & 7) * 16;        // 0..112
        const float* src = x + (size_t)(pix0 + row) * 128 + ch0;
        float f[16];
#pragma unroll
        for (int j = 0; j < 4; j++)
            *(float4*)(f + j * 4) = *(const float4*)(src + j * 4);
#pragma unroll
        for (int c = 0; c < 2; c++) {
            u16x8 hv, lv;
#pragma unroll
            for (int j = 0; j < 8; j++) {
                const float v = f[c * 8 + j];
                const ushort hh = f2bf(v);
                hv[j] = hh;
                lv[j] = f2bf(v - bf2f(hh));
            }
            const int byte = row * 256 + (((ch0 + c * 8) * 2) ^ ((row & 7) << 4));
            *(u16x8*)(sA + byte) = hv;
            *(u16x8*)(sA + 32 * 256 + byte) = lv;
        }
    }
    __syncthreads();
    gemm_tail_lds<2, 2>(BT0h, BT0l, b_in, x_proj, pix0, sA);
    __syncthreads();   // all tail LDS reads done before phase-B overwrites

    // ---- phase B: dwconv + LN + GELU staging, then offset/mask GEMM ----
    {
        const int pl = t >> 5;               // 0..7
        const int cq = (t & 31) << 2;        // channel quad
#pragma unroll
        for (int pass = 0; pass < 4; pass++) {
            const int lpix = pass * 8 + pl;
            const int pix  = pix0 + lpix;
            const int w = pix & 63;
            const int h = (pix >> 6) & 63;
            const int b = pix >> 12;

            float4 acc = make_float4(0.f, 0.f, 0.f, 0.f);
#pragma unroll
            for (int kh = 0; kh < 3; kh++) {
                const int hy = h + kh - 1;
                if (hy < 0 || hy > 63) continue;
#pragma unroll
                for (int kw = 0; kw < 3; kw++) {
                    const int wx = w + kw - 1;
                    if (wx < 0 || wx > 63) continue;
                    const float4 v  = *(const float4*)(x + (((size_t)((b * 64 + hy) * 64 + wx)) << 7) + cq);
                    const float4 kv = *(const float4*)(kern + ((kh * 3 + kw) << 7) + cq);
                    acc.x = fmaf(v.x, kv.x, acc.x);
                    acc.y = fmaf(v.y, kv.y, acc.y);
                    acc.z = fmaf(v.z, kv.z, acc.z);
                    acc.w = fmaf(v.w, kv.w, acc.w);
                }
            }
            const float4 kb = *(const float4*)(kbias + cq);
            acc.x += kb.x; acc.y += kb.y; acc.z += kb.z; acc.w += kb.w;

            float s  = acc.x + acc.y + acc.z + acc.w;
            float s2 = acc.x * acc.x + acc.y * acc.y + acc.z * acc.z + acc.w * acc.w;
#pragma unroll
            for (int m = 16; m >= 1; m >>= 1) {
                s  += __shfl_xor(s, m);
                s2 += __shfl_xor(s2, m);
            }
            const float mu   = s * (1.f / 128.f);
            const float var  = s2 * (1.f / 128.f) - mu * mu;
            const float rstd = 1.f / sqrtf(var + 1e-6f);

            const float4 g  = *(const float4*)(gamma + cq);
            const float4 bb = *(const float4*)(beta + cq);
            const float vv[4] = {acc.x, acc.y, acc.z, acc.w};
            const float gg[4] = {g.x, g.y, g.z, g.w};
            const float be[4] = {bb.x, bb.y, bb.z, bb.w};
            u16x4 hv, lv;
#pragma unroll
            for (int i = 0; i < 4; i++) {
                const float xh = (vv[i] - mu) * rstd * gg[i] + be[i];
                const float gl = 0.5f * xh * (1.f + erff(xh * 0.70710678118654752f));
                const ushort hh = f2bf(gl);
                hv[i] = hh;
                lv[i] = f2bf(gl - bf2f(hh));
            }
            const int byte = lpix * 256 + ((cq * 2) ^ ((lpix & 7) << 4));
            *(u16x4*)(sA + byte) = hv;
            *(u16x4*)(sA + 32 * 256 + byte) = lv;
        }
    }
    __syncthreads();
    gemm_tail_lds<2, 2>(BT1h, BT1l, bpack, offmask, pix0, sA);
}

// ---------------------------------------------------------------------------
// k3: DCNv3 sampling fused with output_proj GEMM.
// 512 threads, 16 pixels/block (grid 1024); thread = (pixel, group, q=0..7),
// 4 channels each -> one corner read = 8 lanes x float4 = 128B contiguous.
// ---------------------------------------------------------------------------
__global__ __launch_bounds__(512) void k3_sample_out(
    const float* __restrict__ xp, const float* __restrict__ om,
    const ushort* __restrict__ BTh, const ushort* __restrict__ BTl,
    const float* __restrict__ bias, float* __restrict__ out)
{
    __shared__ __align__(16) char sA[2 * 16 * 256];
    const int t = threadIdx.x;
    const int q = t & 7;                 // channel quad within group
    const int g = (t >> 3) & 3;          // group
    const int lpix = t >> 5;             // 0..15
    const int pix0 = blockIdx.x * 16;
    const int pix = pix0 + lpix;
    const int w = pix & 63;
    const int h = (pix >> 6) & 63;
    const int b = pix >> 12;

    const float* ompix = om + ((size_t)pix << 7);

    float lg[9];
    float mx = -1e30f;
#pragma unroll
    for (int p = 0; p < 9; p++) {
        lg[p] = ompix[72 + g * 9 + p];
        mx = fmaxf(mx, lg[p]);
    }
    float sum = 0.f;
#pragma unroll
    for (int p = 0; p < 9; p++) { lg[p] = expf(lg[p] - mx); sum += lg[p]; }
    const float inv = 1.f / sum;

    float4 acc = make_float4(0.f, 0.f, 0.f, 0.f);
    const int chbase = g * 32 + q * 4;

#pragma unroll
    for (int p = 0; p < 9; p++) {
        const float ox = ompix[g * 18 + 2 * p];
        const float oy = ompix[g * 18 + 2 * p + 1];
        const float px = (float)(w + p / 3 - 1) + ox;
        const float py = (float)(h + p % 3 - 1) + oy;
        const float fx0 = floorf(px), fy0 = floorf(py);
        const int x0 = (int)fx0, y0 = (int)fy0;
        const float wx1 = px - fx0, wy1 = py - fy0;
        const float wx0 = 1.f - wx1, wy0 = 1.f - wy1;
        const float m = lg[p] * inv;
        const float cw[4] = {wy0 * wx0 * m, wy0 * wx1 * m, wy1 * wx0 * m, wy1 * wx1 * m};
        const int cx[4] = {x0, x0 + 1, x0, x0 + 1};
        const int cy[4] = {y0, y0, y0 + 1, y0 + 1};
#pragma unroll
        for (int c = 0; c < 4; c++) {
            const int xx = cx[c], yy = cy[c];
            if (xx >= 0 && xx < 64 && yy >= 0 && yy < 64) {
                const float* src = xp + (((size_t)((b * 64 + yy) * 64 + xx)) << 7) + chbase;
                const float4 v = *(const float4*)(src);
                const float wt = cw[c];
                acc.x = fmaf(v.x, wt, acc.x);
                acc.y = fmaf(v.y, wt, acc.y);
                acc.z = fmaf(v.z, wt, acc.z);
                acc.w = fmaf(v.w, wt, acc.w);
            }
        }
    }

    // write sampled 4ch as bf16 hi/lo into swizzled LDS
    const float sv[4] = {acc.x, acc.y, acc.z, acc.w};
    u16x4 hv, lv;
#pragma unroll
    for (int j = 0; j < 4; j++) {
        const ushort hh = f2bf(sv[j]);
        hv[j] = hh;
        lv[j] = f2bf(sv[j] - bf2f(hh));
    }
    const int byte = lpix * 256 + ((chbase * 2) ^ ((lpix & 7) << 4));
    *(u16x4*)(sA + byte) = hv;
    *(u16x4*)(sA + 16 * 256 + byte) = lv;
    __syncthreads();
    gemm_tail_lds<1, 1>(BTh, BTl, bias, out, pix0, sA);
}

// ---------------------------------------------------------------------------
extern "C" void kernel_launch(void* const* d_in, const int* in_sizes, int n_in,
                              void* d_out, int out_size, void* d_ws, size_t ws_size,
                              hipStream_t stream)
{
    const float* input   = (const float*)d_in[0];
    const float* w_in    = (const float*)d_in[1];
    const float* b_in    = (const float*)d_in[2];
    const float* w_out   = (const float*)d_in[3];
    const float* b_out   = (const float*)d_in[4];
    const float* w_off   = (const float*)d_in[5];
    const float* b_off   = (const float*)d_in[6];
    const float* w_mask  = (const float*)d_in[7];
    const float* b_mask  = (const float*)d_in[8];
    const float* dw_kern = (const float*)d_in[9];
    const float* dw_bias = (const float*)d_in[10];
    const float* ln_g    = (const float*)d_in[11];
    const float* ln_b    = (const float*)d_in[12];
    float* out = (float*)d_out;

    float* ws      = (float*)d_ws;
    float* x_proj  = ws;                        // M*128
    float* offmask = ws + PIXC;                 // M*128 (72 off | 36 mask | 20 pad)
    ushort* BT     = (ushort*)(ws + 2 * PIXC);  // 3 mats x (hi|lo) x 128 x 128 bf16
    float* bpack   = (float*)(BT + 3 * 32768);  // 128

    prep_weights<<<49, 256, 0, stream>>>(w_in, w_out, w_off, b_off, w_mask, b_mask,
                                         BT, bpack);
    k12_proj_dwln<<<MPIX / 32, 256, 0, stream>>>(input, BT, BT + 16384, b_in, x_proj,
                                                 dw_kern, dw_bias, ln_g, ln_b,
                                                 BT + 32768, BT + 49152, bpack, offmask);
    k3_sample_out<<<MPIX / 16, 512, 0, stream>>>(x_proj, offmask,
                                                 BT + 65536, BT + 81920, b_out, out);
}